// Round 1
// baseline (271.716 us; speedup 1.0000x reference)
//
#include <hip/hip_runtime.h>
#include <cstdint>
#include <cstddef>

// Problem constants
#define B_    128   // batch
#define C_    32    // in channels
#define O_    64    // out channels
#define H_    34    // input H=W
#define OHW   32    // output H=W
#define NPOS  1024  // 32*32 spatial positions
#define K9    9     // 3x3 taps

typedef __bf16 v8bf __attribute__((ext_vector_type(8)));
typedef float  v4f  __attribute__((ext_vector_type(4)));

__device__ __forceinline__ unsigned short f2bf(float f) {
    union { float f; unsigned int u; } v; v.f = f;
    unsigned int u = v.u;
    return (unsigned short)((u + 0x7FFFu + ((u >> 16) & 1u)) >> 16);
}

// ---------------------------------------------------------------------------
// Pass 1: repack x (fp32 [b][c][34][34]) -> x2 (bf16 [h][w][b][c])
// so the main kernel's per-(i,j,kh,kw) P-chunk is one contiguous 8 KB block
// already in MFMA A-fragment layout (c contiguous per b-row).
// ---------------------------------------------------------------------------
__global__ __launch_bounds__(256) void repack_x(const float* __restrict__ x,
                                                unsigned short* __restrict__ x2) {
    const int bh = blockIdx.x;           // b*34 + h
    const int b = bh / H_;
    const int h = bh % H_;
    __shared__ unsigned short tile[C_][H_ + 2];   // pad to 36 for bank spread
    const int t = threadIdx.x;
    // coalesced-ish read along w (34-float runs per c)
    for (int e = t; e < C_ * H_; e += 256) {
        const int c = e / H_, w = e % H_;
        tile[c][w] = f2bf(x[((size_t)(b * C_ + c) * H_ + h) * H_ + w]);
    }
    __syncthreads();
    // coalesced write: 32 consecutive c per (h,w)
    for (int e = t; e < H_ * C_; e += 256) {
        const int w = e >> 5, c = e & 31;
        x2[((size_t)(h * H_ + w) * B_ + b) * C_ + c] = tile[c][w];
    }
}

// ---------------------------------------------------------------------------
// Main: one block per spatial position (i,j). GEMM M=128(b) N=64(o) K=288.
// K-loop: 9 chunks of K=32 (one (kh,kw) tap, all 32 c). Per chunk each of 4
// waves does 2 A-frags + 4 B-frags (ds_read_b128, dense 1KB blocks) + 8 MFMAs.
// Weight (fp32, read-once from HBM) staged to LDS bf16 once per block.
// ---------------------------------------------------------------------------
template <bool USE_X2>
__global__ __launch_bounds__(256) void lc_main(const float* __restrict__ x,
                                               const unsigned short* __restrict__ x2,
                                               const float* __restrict__ weight,
                                               const float* __restrict__ bias,
                                               float* __restrict__ out) {
    __shared__ __align__(16) unsigned short Wl[K9 * O_ * C_]; // 36,864 B
    __shared__ __align__(16) unsigned short Pl[B_ * C_];      //  8,192 B
    __shared__ float biasl[O_];

    const int pos = blockIdx.x;        // i*32 + j
    const int i = pos >> 5;
    const int j = pos & 31;
    const int t = threadIdx.x;

    // ---- stage all weights for this position: 2048 (o,c) pairs x 9 taps ----
    // weight[o][c][i][j][k]: per pair, 9 contiguous floats. Lines shared with
    // j-neighbor blocks -> HBM fetch stays ~= unique weight bytes.
    for (int p = t; p < O_ * C_; p += 256) {
        const float* wp = weight + ((size_t)p * NPOS + pos) * K9;
#pragma unroll
        for (int k = 0; k < K9; ++k)
            Wl[k * (O_ * C_) + p] = f2bf(wp[k]);   // [k][o*32+c], contiguous lanes
    }
    if (t < O_) biasl[t] = bias[(size_t)t * NPOS + pos];

    const int wv = t >> 6;      // wave 0..3 -> b-rows [wv*32, wv*32+32)
    const int l  = t & 63;
    const int lm = l & 15;      // m / n within 16-tile
    const int q  = l >> 4;      // quad -> k-subgroup of 8

    v4f acc[2][4];
#pragma unroll
    for (int a = 0; a < 2; ++a)
#pragma unroll
        for (int n = 0; n < 4; ++n) acc[a][n] = (v4f){0.f, 0.f, 0.f, 0.f};

    for (int k = 0; k < K9; ++k) {
        const int kh = k / 3, kw = k % 3;
        __syncthreads();   // previous chunk's readers done before overwrite
        if (USE_X2) {
            // 8 KB contiguous copy, 16 B per thread x2
            const uint4* src = (const uint4*)(x2 + (size_t)((i + kh) * H_ + (j + kw)) * B_ * C_);
            uint4* dst = (uint4*)Pl;
            dst[t]       = src[t];
            dst[t + 256] = src[t + 256];
        } else {
            // fallback (ws too small): correct but uncoalesced
            for (int e = t; e < B_ * C_; e += 256) {
                const int b = e >> 5, c = e & 31;
                Pl[e] = f2bf(x[((size_t)(b * C_ + c) * H_ + (i + kh)) * H_ + (j + kw)]);
            }
        }
        __syncthreads();

        v8bf af[2], bfr[4];
#pragma unroll
        for (int mt = 0; mt < 2; ++mt) {
            const int row = wv * 32 + mt * 16 + lm;
            af[mt] = *(const v8bf*)&Pl[row * C_ + q * 8];
        }
#pragma unroll
        for (int nt = 0; nt < 4; ++nt) {
            const int oc = nt * 16 + lm;
            bfr[nt] = *(const v8bf*)&Wl[k * (O_ * C_) + oc * C_ + q * 8];
        }
#pragma unroll
        for (int mt = 0; mt < 2; ++mt)
#pragma unroll
            for (int nt = 0; nt < 4; ++nt)
                acc[mt][nt] = __builtin_amdgcn_mfma_f32_16x16x32_bf16(
                    af[mt], bfr[nt], acc[mt][nt], 0, 0, 0);
    }

    // ---- epilogue: D layout col=lane&15 (=o), row=quad*4+reg (=b) ----
#pragma unroll
    for (int mt = 0; mt < 2; ++mt) {
#pragma unroll
        for (int nt = 0; nt < 4; ++nt) {
            const int o = nt * 16 + lm;
            const float bv = biasl[o];
#pragma unroll
            for (int r = 0; r < 4; ++r) {
                const int b = wv * 32 + mt * 16 + q * 4 + r;
                out[(size_t)(b * O_ + o) * NPOS + pos] = acc[mt][nt][r] + bv;
            }
        }
    }
}

// ---------------------------------------------------------------------------
extern "C" void kernel_launch(void* const* d_in, const int* in_sizes, int n_in,
                              void* d_out, int out_size, void* d_ws, size_t ws_size,
                              hipStream_t stream) {
    const float* x      = (const float*)d_in[0];
    const float* weight = (const float*)d_in[1];
    const float* bias   = (const float*)d_in[2];
    float* out          = (float*)d_out;

    const size_t x2_bytes = (size_t)H_ * H_ * B_ * C_ * sizeof(unsigned short); // 9,469,952

    if (ws_size >= x2_bytes) {
        unsigned short* x2 = (unsigned short*)d_ws;
        repack_x<<<B_ * H_, 256, 0, stream>>>(x, x2);
        lc_main<true><<<NPOS, 256, 0, stream>>>(x, x2, weight, bias, out);
    } else {
        lc_main<false><<<NPOS, 256, 0, stream>>>(x, nullptr, weight, bias, out);
    }
}

// Round 2
// 199.774 us; speedup vs baseline: 1.3601x; 1.3601x over previous
//
#include <hip/hip_runtime.h>
#include <cstdint>
#include <cstddef>

// Problem constants
#define B_    128   // batch
#define C_    32    // in channels
#define O_    64    // out channels
#define H_    34    // input H=W (34 = 32+2)
#define NPOS  1024  // 32*32 spatial positions
#define K9    9     // 3x3 taps
#define BC    (B_ * C_)   // 4096
#define BO    (B_ * O_)   // 8192

typedef __bf16 v8bf __attribute__((ext_vector_type(8)));
typedef float  v4f  __attribute__((ext_vector_type(4)));
typedef float  f4u  __attribute__((ext_vector_type(4), aligned(4)));  // unaligned-ok float4

__device__ __forceinline__ unsigned short f2bf(float f) {
    union { float f; unsigned int u; } v; v.f = f;
    unsigned int u = v.u;
    return (unsigned short)((u + 0x7FFFu + ((u >> 16) & 1u)) >> 16);
}

// ---------------------------------------------------------------------------
// Pass 1: repack x (fp32 [b][c][34][34]) -> x2 (bf16 [h][w][b][c]).
// Block = (b-pair, h) so each 128 B line of x2 (64 shorts = 2 b's x 32 c) is
// written wholly by one block -> no partial-line writes.
// ---------------------------------------------------------------------------
__global__ __launch_bounds__(256) void repack_x(const float* __restrict__ x,
                                                unsigned short* __restrict__ x2) {
    const int ph = blockIdx.x;           // (b/2)*34 + h
    const int b0 = (ph / H_) * 2;
    const int h  = ph % H_;
    __shared__ unsigned short tile[2][C_][H_ + 2];
    const int t = threadIdx.x;
    // read: contiguous 34-float runs per (bb,c)
    for (int e = t; e < 2 * C_ * H_; e += 256) {
        const int bb = e / (C_ * H_);
        const int rem = e % (C_ * H_);
        const int c = rem / H_, w = rem % H_;
        tile[bb][c][w] = f2bf(x[(((size_t)(b0 + bb) * C_ + c) * H_ + h) * H_ + w]);
    }
    __syncthreads();
    // write: 64 consecutive shorts (= one full 128 B line) per (h,w)
    for (int e = t; e < H_ * 64; e += 256) {
        const int w = e >> 6;
        const int idx = e & 63;            // bb*32 + c
        x2[((size_t)(h * H_ + w)) * BC + b0 * C_ + idx] = tile[idx >> 5][idx & 31][w];
    }
}

// ---------------------------------------------------------------------------
// Main: one block per spatial position. GEMM M=128(b) N=64(o) K=288(c x 9).
// Weights staged once to LDS (bf16). A-fragments loaded straight from x2
// global (each frag = one contiguous 1 KB dwordx4 wave-load) -> no barriers
// in the K-loop, compiler free to pipeline.
// MODE 2: write ws[pos][b][o] (full-line exclusive).  MODE 1: direct out.
// MODE 0: no-workspace fallback (slow but correct).
// ---------------------------------------------------------------------------
template <int MODE>
__global__ __launch_bounds__(256, 4) void lc_main(const float* __restrict__ x,
                                                  const unsigned short* __restrict__ x2,
                                                  const float* __restrict__ weight,
                                                  const float* __restrict__ bias,
                                                  float* __restrict__ dst) {
    __shared__ __align__(16) unsigned short Wl[K9 * O_ * C_]; // 36,864 B
    __shared__ float biasl[O_];

    const int pos = blockIdx.x;        // i*32 + j
    const int i = pos >> 5;
    const int j = pos & 31;
    const int t = threadIdx.x;

    // ---- stage weights: 2048 (o,c) pairs x 9 taps, 36 B/thread-iter ----
    for (int p = t; p < O_ * C_; p += 256) {
        const float* wp = weight + ((size_t)p * NPOS + pos) * K9;
        f4u w0 = *(const f4u*)wp;          // unaligned dwordx4
        f4u w1 = *(const f4u*)(wp + 4);
        float w8 = wp[8];
        unsigned short s[9];
        s[0] = f2bf(w0[0]); s[1] = f2bf(w0[1]); s[2] = f2bf(w0[2]); s[3] = f2bf(w0[3]);
        s[4] = f2bf(w1[0]); s[5] = f2bf(w1[1]); s[6] = f2bf(w1[2]); s[7] = f2bf(w1[3]);
        s[8] = f2bf(w8);
#pragma unroll
        for (int k = 0; k < K9; ++k)
            Wl[k * (O_ * C_) + p] = s[k];   // [k][o*32+c]
    }
    if (t < O_) biasl[t] = bias[(size_t)t * NPOS + pos];
    __syncthreads();

    const int wv = t >> 6;      // wave -> b-rows [wv*32, wv*32+32)
    const int l  = t & 63;
    const int lm = l & 15;
    const int q  = l >> 4;

    v4f acc[2][4];
#pragma unroll
    for (int a = 0; a < 2; ++a)
#pragma unroll
        for (int n = 0; n < 4; ++n) acc[a][n] = (v4f){0.f, 0.f, 0.f, 0.f};

    if constexpr (MODE >= 1) {
        const unsigned short* xb = x2 + (size_t)(i * H_ + j) * BC;
#pragma unroll
        for (int k = 0; k < K9; ++k) {
            const int off = ((k / 3) * H_ + (k % 3)) * BC;
            v8bf af[2], bfr[4];
#pragma unroll
            for (int mt = 0; mt < 2; ++mt)
                af[mt] = *(const v8bf*)(xb + off + (wv * 32 + mt * 16 + lm) * C_ + q * 8);
#pragma unroll
            for (int nt = 0; nt < 4; ++nt)
                bfr[nt] = *(const v8bf*)&Wl[k * (O_ * C_) + (nt * 16 + lm) * C_ + q * 8];
#pragma unroll
            for (int mt = 0; mt < 2; ++mt)
#pragma unroll
                for (int nt = 0; nt < 4; ++nt)
                    acc[mt][nt] = __builtin_amdgcn_mfma_f32_16x16x32_bf16(
                        af[mt], bfr[nt], acc[mt][nt], 0, 0, 0);
        }
    } else {
        // fallback: gather A straight from fp32 x (slow, correctness only)
        for (int k = 0; k < K9; ++k) {
            const int kh = k / 3, kw = k % 3;
            v8bf af[2], bfr[4];
#pragma unroll
            for (int mt = 0; mt < 2; ++mt) {
                const int b = wv * 32 + mt * 16 + lm;
                union { v8bf v; unsigned short s[8]; } u;
#pragma unroll
                for (int cc = 0; cc < 8; ++cc) {
                    const int c = q * 8 + cc;
                    u.s[cc] = f2bf(x[(((size_t)b * C_ + c) * H_ + (i + kh)) * H_ + (j + kw)]);
                }
                af[mt] = u.v;
            }
#pragma unroll
            for (int nt = 0; nt < 4; ++nt)
                bfr[nt] = *(const v8bf*)&Wl[k * (O_ * C_) + (nt * 16 + lm) * C_ + q * 8];
#pragma unroll
            for (int mt = 0; mt < 2; ++mt)
#pragma unroll
                for (int nt = 0; nt < 4; ++nt)
                    acc[mt][nt] = __builtin_amdgcn_mfma_f32_16x16x32_bf16(
                        af[mt], bfr[nt], acc[mt][nt], 0, 0, 0);
        }
    }

    // ---- epilogue: D layout col(lane&15)=o, row(q*4+r)=b ----
    if constexpr (MODE == 2) {
        float* wsp = dst + (size_t)pos * BO;   // [pos][b][o], block-exclusive 32 KB
#pragma unroll
        for (int mt = 0; mt < 2; ++mt)
#pragma unroll
            for (int nt = 0; nt < 4; ++nt) {
                const int o = nt * 16 + lm;
                const float bv = biasl[o];
#pragma unroll
                for (int r = 0; r < 4; ++r) {
                    const int b = wv * 32 + mt * 16 + q * 4 + r;
                    wsp[b * O_ + o] = acc[mt][nt][r] + bv;
                }
            }
    } else {
#pragma unroll
        for (int mt = 0; mt < 2; ++mt)
#pragma unroll
            for (int nt = 0; nt < 4; ++nt) {
                const int o = nt * 16 + lm;
                const float bv = biasl[o];
#pragma unroll
                for (int r = 0; r < 4; ++r) {
                    const int b = wv * 32 + mt * 16 + q * 4 + r;
                    dst[(size_t)(b * O_ + o) * NPOS + pos] = acc[mt][nt][r] + bv;
                }
            }
    }
}

// ---------------------------------------------------------------------------
// Pass 3: transpose ws [1024 pos][8192 bo] -> out [8192 bo][1024 pos].
// 64x64 fp32 tiles through LDS (+1 pad). Full 128 B lines both sides, each
// line owned by exactly one block.
// ---------------------------------------------------------------------------
__global__ __launch_bounds__(256) void transpose_out(const float* __restrict__ ws,
                                                     float* __restrict__ out) {
    __shared__ float tile[64][65];
    const int tb  = blockIdx.x;            // 0..2047
    const int bo0 = (tb >> 4) * 64;        // 128 bo-tiles
    const int p0  = (tb & 15) * 64;        // 16 pos-tiles
    const int tx  = threadIdx.x & 63;
    const int ty  = threadIdx.x >> 6;
#pragma unroll
    for (int r = 0; r < 16; ++r)
        tile[r * 4 + ty][tx] = ws[(size_t)(p0 + r * 4 + ty) * BO + bo0 + tx];
    __syncthreads();
#pragma unroll
    for (int r = 0; r < 16; ++r)
        out[(size_t)(bo0 + r * 4 + ty) * NPOS + p0 + tx] = tile[tx][r * 4 + ty];
}

// ---------------------------------------------------------------------------
extern "C" void kernel_launch(void* const* d_in, const int* in_sizes, int n_in,
                              void* d_out, int out_size, void* d_ws, size_t ws_size,
                              hipStream_t stream) {
    const float* x      = (const float*)d_in[0];
    const float* weight = (const float*)d_in[1];
    const float* bias   = (const float*)d_in[2];
    float* out          = (float*)d_out;

    const size_t WSB = (size_t)NPOS * BO * sizeof(float);              // 33,554,432
    const size_t X2B = (size_t)H_ * H_ * BC * sizeof(unsigned short);  //  9,469,952

    if (ws_size >= WSB + X2B) {
        float* wsout = (float*)d_ws;
        unsigned short* x2 = (unsigned short*)((char*)d_ws + WSB);
        repack_x<<<(B_ / 2) * H_, 256, 0, stream>>>(x, x2);
        lc_main<2><<<NPOS, 256, 0, stream>>>(x, x2, weight, bias, wsout);
        transpose_out<<<2048, 256, 0, stream>>>(wsout, out);
    } else if (ws_size >= X2B) {
        unsigned short* x2 = (unsigned short*)d_ws;
        repack_x<<<(B_ / 2) * H_, 256, 0, stream>>>(x, x2);
        lc_main<1><<<NPOS, 256, 0, stream>>>(x, x2, weight, bias, out);
    } else {
        lc_main<0><<<NPOS, 256, 0, stream>>>(x, nullptr, weight, bias, out);
    }
}

// Round 3
// 179.282 us; speedup vs baseline: 1.5156x; 1.1143x over previous
//
#include <hip/hip_runtime.h>
#include <cstdint>
#include <cstddef>

// Problem constants
#define B_    128   // batch
#define C_    32    // in channels
#define O_    64    // out channels
#define H_    34    // input H=W (34 = 32+2)
#define NPOS  1024  // 32*32 spatial positions
#define K9    9     // 3x3 taps
#define BC    (B_ * C_)   // 4096
#define BO    (B_ * O_)   // 8192
#define P_    (O_ * C_)   // 2048 (o*32+c)
#define WROW  68          // padded LDS row length (shorts) in repack_w

typedef __bf16 v8bf __attribute__((ext_vector_type(8)));
typedef float  v4f  __attribute__((ext_vector_type(4)));
typedef float  f4u  __attribute__((ext_vector_type(4), aligned(4)));  // unaligned-ok float4

__device__ __forceinline__ unsigned short f2bf(float f) {
    union { float f; unsigned int u; } v; v.f = f;
    unsigned int u = v.u;
    return (unsigned short)((u + 0x7FFFu + ((u >> 16) & 1u)) >> 16);
}
__device__ __forceinline__ float bf2f(unsigned short s) {
    union { unsigned int u; float f; } v; v.u = ((unsigned int)s) << 16;
    return v.f;
}

// ---------------------------------------------------------------------------
// Pass 1a: repack x (fp32 [b][c][34][34]) -> x2 (bf16 [h][w][b][c]).
// Block = (b-pair, h): each 128 B line of x2 (2 b x 32 c) written wholly by
// one block.
// ---------------------------------------------------------------------------
__global__ __launch_bounds__(256) void repack_x(const float* __restrict__ x,
                                                unsigned short* __restrict__ x2) {
    const int ph = blockIdx.x;           // (b/2)*34 + h
    const int b0 = (ph / H_) * 2;
    const int h  = ph % H_;
    __shared__ unsigned short tile[2][C_][H_ + 2];
    const int t = threadIdx.x;
    for (int e = t; e < 2 * C_ * H_; e += 256) {
        const int bb = e / (C_ * H_);
        const int rem = e % (C_ * H_);
        const int c = rem / H_, w = rem % H_;
        tile[bb][c][w] = f2bf(x[(((size_t)(b0 + bb) * C_ + c) * H_ + h) * H_ + w]);
    }
    __syncthreads();
    for (int e = t; e < H_ * 64; e += 256) {
        const int w = e >> 6;
        const int idx = e & 63;            // bb*32 + c
        x2[((size_t)(h * H_ + w)) * BC + b0 * C_ + idx] = tile[idx >> 5][idx & 31][w];
    }
}

// ---------------------------------------------------------------------------
// Pass 1b: repack weight (fp32 [p][pos][k], p=o*32+c) -> w2 (bf16 [pos][k][p]).
// Tile: 64 p x 32 pos x 9 k through LDS. Reads: 64 contiguous 1152 B runs
// (all dwordx4, aligned). Writes: 288 rows of 128 B, each exactly one
// block-exclusive cache line.
// ---------------------------------------------------------------------------
__global__ __launch_bounds__(256) void repack_w(const float* __restrict__ weight,
                                                unsigned short* __restrict__ w2) {
    __shared__ unsigned short tile[32 * 9 * WROW];   // 39,168 B; rows of 64 used
    const int pt   = blockIdx.x >> 5;   // 32 p-tiles
    const int qt   = blockIdx.x & 31;   // 32 pos-tiles
    const int p0   = pt * 64;
    const int pos0 = qt * 32;
    const int t = threadIdx.x;
    // read: 64 p x 72 float4 each (288 floats = 32 pos x 9 k, contiguous)
    for (int e = t; e < 64 * 72; e += 256) {
        const int pl = e / 72;
        const int r4 = e % 72;
        const f4u v = *(const f4u*)(weight + ((size_t)(p0 + pl) * NPOS + pos0) * K9 + r4 * 4);
        const int f0 = r4 * 4;
#pragma unroll
        for (int u = 0; u < 4; ++u) {
            const int f = f0 + u;
            const int pos_l = f / 9, k = f % 9;
            tile[(pos_l * 9 + k) * WROW + pl] = f2bf(v[u]);
        }
    }
    __syncthreads();
    // write: 288 (pos,k) rows x 64 shorts -> one full 128 B line each
    for (int e = t; e < 288 * 16; e += 256) {    // uint2 = 4 shorts
        const int row = e >> 4;                  // pos_l*9 + k
        const int sub = e & 15;
        const uint2 v = *(const uint2*)&tile[row * WROW + sub * 4];
        *(uint2*)(w2 + ((size_t)(pos0 * 9 + row)) * P_ + p0 + sub * 4) = v;
    }
}

// ---------------------------------------------------------------------------
// Main: one block per pos. GEMM M=128(b) N=64(o) K=288. MODE 2: zero LDS,
// zero barriers — A-frags from x2 global, B-frags from w2 global (1 KB
// contiguous wave-loads, L2-served 4x reuse), bf16 ws out.
// MODE 1: no-w2 fallback (stage fp32 weight->LDS).  MODE 0: no-ws fallback.
// ---------------------------------------------------------------------------
template <int MODE>
__global__ __launch_bounds__(256, 4) void lc_main(const float* __restrict__ x,
                                                  const unsigned short* __restrict__ x2,
                                                  const unsigned short* __restrict__ w2,
                                                  const float* __restrict__ weight,
                                                  const float* __restrict__ bias,
                                                  void* __restrict__ dstv) {
    const int bid = blockIdx.x;
    // XCD swizzle: with round-robin block->XCD, this gives each XCD a
    // contiguous pos band (i-rows), so x2/weight lines are reused within one L2.
    const int pos = ((bid & 7) << 7) | (bid >> 3);
    const int i = pos >> 5, j = pos & 31;
    const int t  = threadIdx.x;
    const int wv = t >> 6;
    const int l  = t & 63;
    const int lm = l & 15;
    const int q  = l >> 4;

    float bv[4];
#pragma unroll
    for (int nt = 0; nt < 4; ++nt)
        bv[nt] = bias[(size_t)(nt * 16 + lm) * NPOS + pos];

    v4f acc[2][4];
#pragma unroll
    for (int a = 0; a < 2; ++a)
#pragma unroll
        for (int n = 0; n < 4; ++n) acc[a][n] = (v4f){0.f, 0.f, 0.f, 0.f};

    if constexpr (MODE == 2) {
        const unsigned short* xb = x2 + (size_t)(i * H_ + j) * BC;
        const unsigned short* wb = w2 + (size_t)pos * (K9 * P_);
#pragma unroll
        for (int k = 0; k < K9; ++k) {
            const int off = ((k / 3) * H_ + (k % 3)) * BC;
            v8bf af[2], bfr[4];
#pragma unroll
            for (int mt = 0; mt < 2; ++mt)
                af[mt] = *(const v8bf*)(xb + off + (wv * 32 + mt * 16 + lm) * C_ + q * 8);
#pragma unroll
            for (int nt = 0; nt < 4; ++nt)
                bfr[nt] = *(const v8bf*)(wb + k * P_ + (nt * 16 + lm) * C_ + q * 8);
#pragma unroll
            for (int mt = 0; mt < 2; ++mt)
#pragma unroll
                for (int nt = 0; nt < 4; ++nt)
                    acc[mt][nt] = __builtin_amdgcn_mfma_f32_16x16x32_bf16(
                        af[mt], bfr[nt], acc[mt][nt], 0, 0, 0);
        }
    } else if constexpr (MODE == 1) {
        __shared__ __align__(16) unsigned short Wl[K9 * P_];  // 36,864 B
        for (int p = t; p < P_; p += 256) {
            const float* wp = weight + ((size_t)p * NPOS + pos) * K9;
            f4u w0 = *(const f4u*)wp;
            f4u w1 = *(const f4u*)(wp + 4);
            float w8 = wp[8];
            unsigned short s[9];
            s[0] = f2bf(w0[0]); s[1] = f2bf(w0[1]); s[2] = f2bf(w0[2]); s[3] = f2bf(w0[3]);
            s[4] = f2bf(w1[0]); s[5] = f2bf(w1[1]); s[6] = f2bf(w1[2]); s[7] = f2bf(w1[3]);
            s[8] = f2bf(w8);
#pragma unroll
            for (int k = 0; k < K9; ++k) Wl[k * P_ + p] = s[k];
        }
        __syncthreads();
        const unsigned short* xb = x2 + (size_t)(i * H_ + j) * BC;
#pragma unroll
        for (int k = 0; k < K9; ++k) {
            const int off = ((k / 3) * H_ + (k % 3)) * BC;
            v8bf af[2], bfr[4];
#pragma unroll
            for (int mt = 0; mt < 2; ++mt)
                af[mt] = *(const v8bf*)(xb + off + (wv * 32 + mt * 16 + lm) * C_ + q * 8);
#pragma unroll
            for (int nt = 0; nt < 4; ++nt)
                bfr[nt] = *(const v8bf*)&Wl[k * P_ + (nt * 16 + lm) * C_ + q * 8];
#pragma unroll
            for (int mt = 0; mt < 2; ++mt)
#pragma unroll
                for (int nt = 0; nt < 4; ++nt)
                    acc[mt][nt] = __builtin_amdgcn_mfma_f32_16x16x32_bf16(
                        af[mt], bfr[nt], acc[mt][nt], 0, 0, 0);
        }
    } else {
        // no-workspace fallback: gather everything straight from fp32 inputs
        for (int k = 0; k < K9; ++k) {
            const int kh = k / 3, kw = k % 3;
            v8bf af[2], bfr[4];
#pragma unroll
            for (int mt = 0; mt < 2; ++mt) {
                const int b = wv * 32 + mt * 16 + lm;
                union { v8bf v; unsigned short s[8]; } u;
#pragma unroll
                for (int cc = 0; cc < 8; ++cc)
                    u.s[cc] = f2bf(x[(((size_t)b * C_ + q * 8 + cc) * H_ + (i + kh)) * H_ + (j + kw)]);
                af[mt] = u.v;
            }
#pragma unroll
            for (int nt = 0; nt < 4; ++nt) {
                union { v8bf v; unsigned short s[8]; } u;
#pragma unroll
                for (int cc = 0; cc < 8; ++cc) {
                    const int p = (nt * 16 + lm) * C_ + q * 8 + cc;
                    u.s[cc] = f2bf(weight[((size_t)p * NPOS + pos) * K9 + k]);
                }
                bfr[nt] = u.v;
            }
#pragma unroll
            for (int mt = 0; mt < 2; ++mt)
#pragma unroll
                for (int nt = 0; nt < 4; ++nt)
                    acc[mt][nt] = __builtin_amdgcn_mfma_f32_16x16x32_bf16(
                        af[mt], bfr[nt], acc[mt][nt], 0, 0, 0);
        }
    }

    // ---- epilogue: D layout col(lane&15)=o, row(q*4+r)=b ----
    if constexpr (MODE >= 1) {
        unsigned short* wsp = (unsigned short*)dstv + (size_t)pos * BO; // [pos][b][o]
#pragma unroll
        for (int mt = 0; mt < 2; ++mt)
#pragma unroll
            for (int nt = 0; nt < 4; ++nt) {
                const int o = nt * 16 + lm;
#pragma unroll
                for (int r = 0; r < 4; ++r) {
                    const int b = wv * 32 + mt * 16 + q * 4 + r;
                    wsp[b * O_ + o] = f2bf(acc[mt][nt][r] + bv[nt]);
                }
            }
    } else {
        float* outp = (float*)dstv;
#pragma unroll
        for (int mt = 0; mt < 2; ++mt)
#pragma unroll
            for (int nt = 0; nt < 4; ++nt) {
                const int o = nt * 16 + lm;
#pragma unroll
                for (int r = 0; r < 4; ++r) {
                    const int b = wv * 32 + mt * 16 + q * 4 + r;
                    outp[(size_t)(b * O_ + o) * NPOS + pos] = acc[mt][nt][r] + bv[nt];
                }
            }
    }
}

// ---------------------------------------------------------------------------
// Pass 3: transpose ws bf16 [1024 pos][8192 bo] -> out fp32 [bo][pos].
// 64x64 tiles through fp32 LDS (+1 pad -> conflict-free column reads).
// Full lines both sides, each line owned by one block.
// ---------------------------------------------------------------------------
__global__ __launch_bounds__(256) void transpose_out(const unsigned short* __restrict__ ws,
                                                     float* __restrict__ out) {
    __shared__ float tile[64][65];
    const int tb  = blockIdx.x;            // 0..2047
    const int bo0 = (tb >> 4) * 64;
    const int p0  = (tb & 15) * 64;
    const int tx  = threadIdx.x & 63;
    const int ty  = threadIdx.x >> 6;
#pragma unroll
    for (int r = 0; r < 16; ++r)
        tile[r * 4 + ty][tx] = bf2f(ws[(size_t)(p0 + r * 4 + ty) * BO + bo0 + tx]);
    __syncthreads();
#pragma unroll
    for (int r = 0; r < 16; ++r)
        out[(size_t)(bo0 + r * 4 + ty) * NPOS + p0 + tx] = tile[tx][r * 4 + ty];
}

// ---------------------------------------------------------------------------
extern "C" void kernel_launch(void* const* d_in, const int* in_sizes, int n_in,
                              void* d_out, int out_size, void* d_ws, size_t ws_size,
                              hipStream_t stream) {
    const float* x      = (const float*)d_in[0];
    const float* weight = (const float*)d_in[1];
    const float* bias   = (const float*)d_in[2];
    float* out          = (float*)d_out;

    const size_t WSB = (size_t)NPOS * BO * sizeof(unsigned short);        // 16,777,216
    const size_t X2B = (size_t)H_ * H_ * BC * sizeof(unsigned short);     //  9,469,952
    const size_t W2B = (size_t)NPOS * K9 * P_ * sizeof(unsigned short);   // 37,748,736

    if (ws_size >= WSB + X2B + W2B) {
        unsigned short* wsout = (unsigned short*)d_ws;
        unsigned short* x2 = (unsigned short*)((char*)d_ws + WSB);
        unsigned short* w2 = (unsigned short*)((char*)d_ws + WSB + X2B);
        repack_x<<<(B_ / 2) * H_, 256, 0, stream>>>(x, x2);
        repack_w<<<1024, 256, 0, stream>>>(weight, w2);
        lc_main<2><<<NPOS, 256, 0, stream>>>(x, x2, w2, weight, bias, wsout);
        transpose_out<<<2048, 256, 0, stream>>>(wsout, out);
    } else if (ws_size >= WSB + X2B) {
        unsigned short* wsout = (unsigned short*)d_ws;
        unsigned short* x2 = (unsigned short*)((char*)d_ws + WSB);
        repack_x<<<(B_ / 2) * H_, 256, 0, stream>>>(x, x2);
        lc_main<1><<<NPOS, 256, 0, stream>>>(x, x2, nullptr, weight, bias, wsout);
        transpose_out<<<2048, 256, 0, stream>>>(wsout, out);
    } else {
        lc_main<0><<<NPOS, 256, 0, stream>>>(x, nullptr, nullptr, weight, bias, out);
    }
}

// Round 4
// 175.157 us; speedup vs baseline: 1.5513x; 1.0235x over previous
//
#include <hip/hip_runtime.h>
#include <cstdint>
#include <cstddef>

// Problem constants
#define B_    128   // batch
#define C_    32    // in channels
#define O_    64    // out channels
#define H_    34    // input H=W (34 = 32+2)
#define NPOS  1024  // 32*32 spatial positions
#define K9    9     // 3x3 taps
#define BC    (B_ * C_)   // 4096
#define BO    (B_ * O_)   // 8192
#define P_    (O_ * C_)   // 2048 (o*32+c)

typedef __bf16 v8bf __attribute__((ext_vector_type(8)));
typedef float  v4f  __attribute__((ext_vector_type(4)));
typedef float  f4u  __attribute__((ext_vector_type(4), aligned(4)));  // dword-aligned float4

__device__ __forceinline__ unsigned short f2bf(float f) {
    union { float f; unsigned int u; } v; v.f = f;
    unsigned int u = v.u;
    return (unsigned short)((u + 0x7FFFu + ((u >> 16) & 1u)) >> 16);
}
__device__ __forceinline__ float bf2f(unsigned short s) {
    union { unsigned int u; float f; } v; v.u = ((unsigned int)s) << 16;
    return v.f;
}

// ---------------------------------------------------------------------------
// Pass 1: repack x (fp32 [b][c][34][34]) -> x2 (bf16 [h][w][b][c]).
// Block = (b-pair, h): each 128 B line of x2 (2 b x 32 c) written wholly by
// one block.
// ---------------------------------------------------------------------------
__global__ __launch_bounds__(256) void repack_x(const float* __restrict__ x,
                                                unsigned short* __restrict__ x2) {
    const int ph = blockIdx.x;           // (b/2)*34 + h
    const int b0 = (ph / H_) * 2;
    const int h  = ph % H_;
    __shared__ unsigned short tile[2][C_][H_ + 2];
    const int t = threadIdx.x;
    for (int e = t; e < 2 * C_ * H_; e += 256) {
        const int bb = e / (C_ * H_);
        const int rem = e % (C_ * H_);
        const int c = rem / H_, w = rem % H_;
        tile[bb][c][w] = f2bf(x[(((size_t)(b0 + bb) * C_ + c) * H_ + h) * H_ + w]);
    }
    __syncthreads();
    for (int e = t; e < H_ * 64; e += 256) {
        const int w = e >> 6;
        const int idx = e & 63;            // bb*32 + c
        x2[((size_t)(h * H_ + w)) * BC + b0 * C_ + idx] = tile[idx >> 5][idx & 31][w];
    }
}

// ---------------------------------------------------------------------------
// Main: one block per pos (grid 1024 = exactly 4 blocks/CU, 36.9 KB LDS).
// GEMM M=128(b) N=64(o) K=288(c x 9 taps).
// Weight read DIRECTLY from fp32 (9 floats per (o,c), 2x dwordx4 + 1),
// converted to bf16 and staged to LDS in B-frag layout [k][o*32+c].
// XCD swizzle makes the ~3.5 pos that share each weight cache line
// co-resident on one XCD -> unique-line L2 traffic ~= 75.5 MB (no repack_w
// pass needed). A-frags straight from x2 global (1 KB contiguous wave-loads).
// MODE 1: bf16 ws[pos][b][o] out.  MODE 0: no-workspace fallback.
// ---------------------------------------------------------------------------
template <int MODE>
__global__ __launch_bounds__(256, 4) void lc_main(const float* __restrict__ x,
                                                  const unsigned short* __restrict__ x2,
                                                  const float* __restrict__ weight,
                                                  const float* __restrict__ bias,
                                                  void* __restrict__ dstv) {
    const int bid = blockIdx.x;
    // XCD swizzle: round-robin block->XCD => each XCD gets a contiguous
    // 128-pos band; weight/x2 line-sharing neighbors live in one L2.
    const int pos = ((bid & 7) << 7) | (bid >> 3);
    const int i = pos >> 5, j = pos & 31;
    const int t  = threadIdx.x;
    const int wv = t >> 6;
    const int l  = t & 63;
    const int lm = l & 15;
    const int q  = l >> 4;

    float bv[4];
#pragma unroll
    for (int nt = 0; nt < 4; ++nt)
        bv[nt] = bias[(size_t)(nt * 16 + lm) * NPOS + pos];

    v4f acc[2][4];
#pragma unroll
    for (int a = 0; a < 2; ++a)
#pragma unroll
        for (int n = 0; n < 4; ++n) acc[a][n] = (v4f){0.f, 0.f, 0.f, 0.f};

    if constexpr (MODE == 1) {
        __shared__ __align__(16) unsigned short Wl[K9 * P_];  // 36,864 B
        // ---- stage weights: 8 p's per thread, 36 B each ----
#pragma unroll
        for (int pp = 0; pp < 8; ++pp) {
            const int p = pp * 256 + t;
            const float* wp = weight + ((size_t)p * NPOS + pos) * K9;
            f4u w0 = *(const f4u*)wp;
            f4u w1 = *(const f4u*)(wp + 4);
            float w8 = wp[8];
            unsigned short s[9];
            s[0] = f2bf(w0[0]); s[1] = f2bf(w0[1]); s[2] = f2bf(w0[2]); s[3] = f2bf(w0[3]);
            s[4] = f2bf(w1[0]); s[5] = f2bf(w1[1]); s[6] = f2bf(w1[2]); s[7] = f2bf(w1[3]);
            s[8] = f2bf(w8);
#pragma unroll
            for (int k = 0; k < K9; ++k)
                Wl[k * P_ + p] = s[k];       // consecutive lanes -> consecutive shorts
        }
        __syncthreads();

        const unsigned short* xb = x2 + (size_t)(i * H_ + j) * BC;
#pragma unroll
        for (int k = 0; k < K9; ++k) {
            const int off = ((k / 3) * H_ + (k % 3)) * BC;
            v8bf af[2], bfr[4];
#pragma unroll
            for (int mt = 0; mt < 2; ++mt)
                af[mt] = *(const v8bf*)(xb + off + (wv * 32 + mt * 16 + lm) * C_ + q * 8);
#pragma unroll
            for (int nt = 0; nt < 4; ++nt)
                bfr[nt] = *(const v8bf*)&Wl[k * P_ + (nt * 16 + lm) * C_ + q * 8];
#pragma unroll
            for (int mt = 0; mt < 2; ++mt)
#pragma unroll
                for (int nt = 0; nt < 4; ++nt)
                    acc[mt][nt] = __builtin_amdgcn_mfma_f32_16x16x32_bf16(
                        af[mt], bfr[nt], acc[mt][nt], 0, 0, 0);
        }
    } else {
        // no-workspace fallback: gather everything straight from fp32 inputs
        for (int k = 0; k < K9; ++k) {
            const int kh = k / 3, kw = k % 3;
            v8bf af[2], bfr[4];
#pragma unroll
            for (int mt = 0; mt < 2; ++mt) {
                const int b = wv * 32 + mt * 16 + lm;
                union { v8bf v; unsigned short s[8]; } u;
#pragma unroll
                for (int cc = 0; cc < 8; ++cc)
                    u.s[cc] = f2bf(x[(((size_t)b * C_ + q * 8 + cc) * H_ + (i + kh)) * H_ + (j + kw)]);
                af[mt] = u.v;
            }
#pragma unroll
            for (int nt = 0; nt < 4; ++nt) {
                union { v8bf v; unsigned short s[8]; } u;
#pragma unroll
                for (int cc = 0; cc < 8; ++cc) {
                    const int p = (nt * 16 + lm) * C_ + q * 8 + cc;
                    u.s[cc] = f2bf(weight[((size_t)p * NPOS + pos) * K9 + k]);
                }
                bfr[nt] = u.v;
            }
#pragma unroll
            for (int mt = 0; mt < 2; ++mt)
#pragma unroll
                for (int nt = 0; nt < 4; ++nt)
                    acc[mt][nt] = __builtin_amdgcn_mfma_f32_16x16x32_bf16(
                        af[mt], bfr[nt], acc[mt][nt], 0, 0, 0);
        }
    }

    // ---- epilogue: D layout col(lane&15)=o, row(q*4+r)=b ----
    if constexpr (MODE == 1) {
        unsigned short* wsp = (unsigned short*)dstv + (size_t)pos * BO; // [pos][b][o]
#pragma unroll
        for (int mt = 0; mt < 2; ++mt)
#pragma unroll
            for (int nt = 0; nt < 4; ++nt) {
                const int o = nt * 16 + lm;
#pragma unroll
                for (int r = 0; r < 4; ++r) {
                    const int b = wv * 32 + mt * 16 + q * 4 + r;
                    wsp[b * O_ + o] = f2bf(acc[mt][nt][r] + bv[nt]);
                }
            }
    } else {
        float* outp = (float*)dstv;
#pragma unroll
        for (int mt = 0; mt < 2; ++mt)
#pragma unroll
            for (int nt = 0; nt < 4; ++nt) {
                const int o = nt * 16 + lm;
#pragma unroll
                for (int r = 0; r < 4; ++r) {
                    const int b = wv * 32 + mt * 16 + q * 4 + r;
                    outp[(size_t)(b * O_ + o) * NPOS + pos] = acc[mt][nt][r] + bv[nt];
                }
            }
    }
}

// ---------------------------------------------------------------------------
// Pass 3: transpose ws bf16 [1024 pos][8192 bo] -> out fp32 [bo][pos].
// 64x64 tiles through fp32 LDS (+1 pad -> conflict-free column reads).
// Full lines both sides, each line owned by one block.
// ---------------------------------------------------------------------------
__global__ __launch_bounds__(256) void transpose_out(const unsigned short* __restrict__ ws,
                                                     float* __restrict__ out) {
    __shared__ float tile[64][65];
    const int tb  = blockIdx.x;            // 0..2047
    const int bo0 = (tb >> 4) * 64;
    const int p0  = (tb & 15) * 64;
    const int tx  = threadIdx.x & 63;
    const int ty  = threadIdx.x >> 6;
#pragma unroll
    for (int r = 0; r < 16; ++r)
        tile[r * 4 + ty][tx] = bf2f(ws[(size_t)(p0 + r * 4 + ty) * BO + bo0 + tx]);
    __syncthreads();
#pragma unroll
    for (int r = 0; r < 16; ++r)
        out[(size_t)(bo0 + r * 4 + ty) * NPOS + p0 + tx] = tile[tx][r * 4 + ty];
}

// ---------------------------------------------------------------------------
extern "C" void kernel_launch(void* const* d_in, const int* in_sizes, int n_in,
                              void* d_out, int out_size, void* d_ws, size_t ws_size,
                              hipStream_t stream) {
    const float* x      = (const float*)d_in[0];
    const float* weight = (const float*)d_in[1];
    const float* bias   = (const float*)d_in[2];
    float* out          = (float*)d_out;

    const size_t WSB = (size_t)NPOS * BO * sizeof(unsigned short);        // 16,777,216
    const size_t X2B = (size_t)H_ * H_ * BC * sizeof(unsigned short);     //  9,469,952

    if (ws_size >= WSB + X2B) {
        unsigned short* wsout = (unsigned short*)d_ws;
        unsigned short* x2 = (unsigned short*)((char*)d_ws + WSB);
        repack_x<<<(B_ / 2) * H_, 256, 0, stream>>>(x, x2);
        lc_main<1><<<NPOS, 256, 0, stream>>>(x, x2, weight, bias, wsout);
        transpose_out<<<2048, 256, 0, stream>>>(wsout, out);
    } else {
        lc_main<0><<<NPOS, 256, 0, stream>>>(x, nullptr, weight, bias, out);
    }
}

// Round 5
// 167.822 us; speedup vs baseline: 1.6191x; 1.0437x over previous
//
#include <hip/hip_runtime.h>
#include <cstdint>
#include <cstddef>

// Problem constants
#define B_    128   // batch
#define C_    32    // in channels
#define O_    64    // out channels
#define H_    34    // input H=W (34 = 32+2)
#define NPOS  1024  // 32*32 spatial positions
#define K9    9     // 3x3 taps
#define BC    (B_ * C_)   // 4096
#define BO    (B_ * O_)   // 8192

typedef __bf16 v8bf __attribute__((ext_vector_type(8)));
typedef float  v4f  __attribute__((ext_vector_type(4)));
typedef float  f2u  __attribute__((ext_vector_type(2), aligned(4)));  // dword-aligned float2

__device__ __forceinline__ unsigned short f2bf(float f) {
    union { float f; unsigned int u; } v; v.f = f;
    unsigned int u = v.u;
    return (unsigned short)((u + 0x7FFFu + ((u >> 16) & 1u)) >> 16);
}
__device__ __forceinline__ float bf2f(unsigned short s) {
    union { unsigned int u; float f; } v; v.u = ((unsigned int)s) << 16;
    return v.f;
}

// ---------------------------------------------------------------------------
// Pass 1: repack x (fp32 [b][c][34][34]) -> x2 (bf16 [h][w][b][c]).
// ---------------------------------------------------------------------------
__global__ __launch_bounds__(256) void repack_x(const float* __restrict__ x,
                                                unsigned short* __restrict__ x2) {
    const int ph = blockIdx.x;           // (b/2)*34 + h
    const int b0 = (ph / H_) * 2;
    const int h  = ph % H_;
    __shared__ unsigned short tile[2][C_][H_ + 2];
    const int t = threadIdx.x;
    for (int e = t; e < 2 * C_ * H_; e += 256) {
        const int bb = e / (C_ * H_);
        const int rem = e % (C_ * H_);
        const int c = rem / H_, w = rem % H_;
        tile[bb][c][w] = f2bf(x[(((size_t)(b0 + bb) * C_ + c) * H_ + h) * H_ + w]);
    }
    __syncthreads();
    for (int e = t; e < H_ * 64; e += 256) {
        const int w = e >> 6;
        const int idx = e & 63;            // bb*32 + c
        x2[((size_t)(h * H_ + w)) * BC + b0 * C_ + idx] = tile[idx >> 5][idx & 31][w];
    }
}

// ---------------------------------------------------------------------------
// Main (fused): block = (i, j-quarter of 4, o-quarter of 16).
// Per block: 4 independent GEMMs (one per j), M=128 b, N=16 o, K=288 (9 taps
// x 32 c), sharing the weight staging. The block's weight slice is, per
// p=o*32+c, a CONTIGUOUS 144 B run (4 j x 9 k) -> staging is dense dwordx2
// wave-loads (vs 64-line-divergent gather in the per-pos design).
// LDS Wl[j*9+k][p_local] = B-frag layout. Zero barriers in the K-loop.
// Grid mapping: jq = bid&7 -> block's XCD (round-robin bid%8) owns one
// j-column band; all i and all oq co-resident per XCD for x2/weight reuse.
// Output: ws bf16 [pos][o][b] (block owns all b -> full-line writes).
// ---------------------------------------------------------------------------
__global__ __launch_bounds__(256, 4) void lc_fused(const unsigned short* __restrict__ x2,
                                                   const float* __restrict__ weight,
                                                   const float* __restrict__ bias,
                                                   unsigned short* __restrict__ ws) {
    __shared__ __align__(16) unsigned short Wl[36 * 512];  // 36,864 B

    const int bid = blockIdx.x;
    const int jq = bid & 7;            // j-quarter (4 j's) -> XCD id
    const int i  = (bid >> 3) & 31;
    const int oq = bid >> 8;           // o-quarter (16 o's)
    const int j0 = jq * 4;
    const int o0 = oq * 16;
    const int posbase = i * 32 + j0;
    const int t = threadIdx.x;

    // ---- stage weights: 512 p x 36 floats (contiguous run per p) ----
    // element (p_local, d) at wbase + p_local*9216 + d ; d = jj*9 + k
    const float* wbase = weight + ((size_t)(o0 * C_) * NPOS + posbase) * K9;
#pragma unroll
    for (int r = 0; r < 36; ++r) {
        const int idx = r * 256 + t;          // 0..9215
        const int pl = idx / 18;              // p_local 0..511
        const int d2 = idx % 18;              // dwordx2 index 0..17
        const f2u v = *(const f2u*)(wbase + (size_t)pl * (NPOS * K9) + d2 * 2);
        const int d = d2 * 2;                 // jk-flat row
        Wl[d * 512 + pl]       = f2bf(v[0]);
        Wl[(d + 1) * 512 + pl] = f2bf(v[1]);
    }
    __syncthreads();

    const int wv = t >> 6;      // wave -> b-band [wv*32, wv*32+32)
    const int l  = t & 63;
    const int lm = l & 15;      // = o_local (B n-index) / A m-index
    const int q  = l >> 4;

    v4f acc[4][2];              // [jj][mt]
#pragma unroll
    for (int a = 0; a < 4; ++a)
#pragma unroll
        for (int m = 0; m < 2; ++m) acc[a][m] = (v4f){0.f, 0.f, 0.f, 0.f};

#pragma unroll
    for (int tap = 0; tap < K9; ++tap) {
        const int kh = tap / 3, kw = tap % 3;
        const int rowbase = (i + kh) * H_ + j0 + kw;
#pragma unroll
        for (int jj = 0; jj < 4; ++jj) {
            const v8bf bfr = *(const v8bf*)&Wl[(jj * K9 + tap) * 512 + lm * C_ + q * 8];
            const unsigned short* xrow = x2 + (size_t)(rowbase + jj) * BC;
            const v8bf af0 = *(const v8bf*)(xrow + (wv * 32 + lm) * C_ + q * 8);
            const v8bf af1 = *(const v8bf*)(xrow + (wv * 32 + 16 + lm) * C_ + q * 8);
            acc[jj][0] = __builtin_amdgcn_mfma_f32_16x16x32_bf16(af0, bfr, acc[jj][0], 0, 0, 0);
            acc[jj][1] = __builtin_amdgcn_mfma_f32_16x16x32_bf16(af1, bfr, acc[jj][1], 0, 0, 0);
        }
    }

    // ---- epilogue: D col(lane&15)=o_local, row(q*4+r)=b_local ----
    // ws[pos][o][b]: per (jj,mt) one 8-B store per lane (4 consecutive b)
#pragma unroll
    for (int jj = 0; jj < 4; ++jj) {
        const int pos = posbase + jj;
        const float bv = bias[(size_t)(o0 + lm) * NPOS + pos];
        unsigned short* wp = ws + (size_t)pos * BO + (o0 + lm) * B_;
#pragma unroll
        for (int mt = 0; mt < 2; ++mt) {
            const int b = wv * 32 + mt * 16 + q * 4;
            ushort4 pk;
            pk.x = f2bf(acc[jj][mt][0] + bv);
            pk.y = f2bf(acc[jj][mt][1] + bv);
            pk.z = f2bf(acc[jj][mt][2] + bv);
            pk.w = f2bf(acc[jj][mt][3] + bv);
            *(ushort4*)(wp + b) = pk;
        }
    }
}

// ---------------------------------------------------------------------------
// Fallback (no workspace): per-pos kernel gathering straight from fp32.
// ---------------------------------------------------------------------------
__global__ __launch_bounds__(256) void lc_fallback(const float* __restrict__ x,
                                                   const float* __restrict__ weight,
                                                   const float* __restrict__ bias,
                                                   float* __restrict__ out) {
    const int pos = blockIdx.x;
    const int i = pos >> 5, j = pos & 31;
    const int t  = threadIdx.x;
    const int wv = t >> 6;
    const int l  = t & 63;
    const int lm = l & 15;
    const int q  = l >> 4;

    float bv[4];
#pragma unroll
    for (int nt = 0; nt < 4; ++nt)
        bv[nt] = bias[(size_t)(nt * 16 + lm) * NPOS + pos];

    v4f acc[2][4];
#pragma unroll
    for (int a = 0; a < 2; ++a)
#pragma unroll
        for (int n = 0; n < 4; ++n) acc[a][n] = (v4f){0.f, 0.f, 0.f, 0.f};

    for (int k = 0; k < K9; ++k) {
        const int kh = k / 3, kw = k % 3;
        v8bf af[2], bfr[4];
#pragma unroll
        for (int mt = 0; mt < 2; ++mt) {
            const int b = wv * 32 + mt * 16 + lm;
            union { v8bf v; unsigned short s[8]; } u;
#pragma unroll
            for (int cc = 0; cc < 8; ++cc)
                u.s[cc] = f2bf(x[(((size_t)b * C_ + q * 8 + cc) * H_ + (i + kh)) * H_ + (j + kw)]);
            af[mt] = u.v;
        }
#pragma unroll
        for (int nt = 0; nt < 4; ++nt) {
            union { v8bf v; unsigned short s[8]; } u;
#pragma unroll
            for (int cc = 0; cc < 8; ++cc) {
                const int p = (nt * 16 + lm) * C_ + q * 8 + cc;
                u.s[cc] = f2bf(weight[((size_t)p * NPOS + pos) * K9 + k]);
            }
            bfr[nt] = u.v;
        }
#pragma unroll
        for (int mt = 0; mt < 2; ++mt)
#pragma unroll
            for (int nt = 0; nt < 4; ++nt)
                acc[mt][nt] = __builtin_amdgcn_mfma_f32_16x16x32_bf16(
                    af[mt], bfr[nt], acc[mt][nt], 0, 0, 0);
    }
#pragma unroll
    for (int mt = 0; mt < 2; ++mt)
#pragma unroll
        for (int nt = 0; nt < 4; ++nt) {
            const int o = nt * 16 + lm;
#pragma unroll
            for (int r = 0; r < 4; ++r) {
                const int b = wv * 32 + mt * 16 + q * 4 + r;
                out[(size_t)(b * O_ + o) * NPOS + pos] = acc[mt][nt][r] + bv[nt];
            }
        }
}

// ---------------------------------------------------------------------------
// Pass 3: ws bf16 [pos][o][b] -> out fp32 [b][o][pos].
// Block = (o, b-tile of 64, pos-tile of 64); 64x64 tile via LDS (+1 pad).
// Reads: 64 consecutive b per row (128 B). Writes: 64 consecutive pos
// (256 B), each out line written by exactly one block.
// ---------------------------------------------------------------------------
__global__ __launch_bounds__(256) void transpose_out(const unsigned short* __restrict__ ws,
                                                     float* __restrict__ out) {
    __shared__ float tile[64][65];
    const int tb = blockIdx.x;             // 0..2047
    const int o  = tb >> 5;                // 64
    const int bt = (tb >> 4) & 1;          // 2 b-tiles
    const int pt = tb & 15;                // 16 pos-tiles
    const int b0 = bt * 64;
    const int p0 = pt * 64;
    const int tx = threadIdx.x & 63;
    const int ty = threadIdx.x >> 6;
#pragma unroll
    for (int r = 0; r < 16; ++r) {
        const int pr = r * 4 + ty;
        tile[pr][tx] = bf2f(ws[(size_t)(p0 + pr) * BO + o * B_ + b0 + tx]);
    }
    __syncthreads();
#pragma unroll
    for (int r = 0; r < 16; ++r) {
        const int br = r * 4 + ty;
        out[((size_t)(b0 + br) * O_ + o) * NPOS + p0 + tx] = tile[tx][br];
    }
}

// ---------------------------------------------------------------------------
extern "C" void kernel_launch(void* const* d_in, const int* in_sizes, int n_in,
                              void* d_out, int out_size, void* d_ws, size_t ws_size,
                              hipStream_t stream) {
    const float* x      = (const float*)d_in[0];
    const float* weight = (const float*)d_in[1];
    const float* bias   = (const float*)d_in[2];
    float* out          = (float*)d_out;

    const size_t WSB = (size_t)NPOS * BO * sizeof(unsigned short);        // 16,777,216
    const size_t X2B = (size_t)H_ * H_ * BC * sizeof(unsigned short);     //  9,469,952

    if (ws_size >= WSB + X2B) {
        unsigned short* wsout = (unsigned short*)d_ws;
        unsigned short* x2 = (unsigned short*)((char*)d_ws + WSB);
        repack_x<<<(B_ / 2) * H_, 256, 0, stream>>>(x, x2);
        lc_fused<<<1024, 256, 0, stream>>>(x2, weight, bias, wsout);
        transpose_out<<<2048, 256, 0, stream>>>(wsout, out);
    } else {
        lc_fallback<<<NPOS, 256, 0, stream>>>(x, weight, bias, out);
    }
}

// Round 6
// 164.737 us; speedup vs baseline: 1.6494x; 1.0187x over previous
//
#include <hip/hip_runtime.h>
#include <cstdint>
#include <cstddef>

// Problem constants
#define B_    128   // batch
#define C_    32    // in channels
#define O_    64    // out channels
#define H_    34    // input H=W (34 = 32+2)
#define NPOS  1024  // 32*32 spatial positions
#define K9    9     // 3x3 taps
#define BC    (B_ * C_)   // 4096
#define BO    (B_ * O_)   // 8192

typedef __bf16 v8bf __attribute__((ext_vector_type(8)));
typedef float  v4f  __attribute__((ext_vector_type(4)));
typedef float  f4a  __attribute__((ext_vector_type(4)));              // 16-B aligned float4

__device__ __forceinline__ unsigned short f2bf(float f) {
    union { float f; unsigned int u; } v; v.f = f;
    unsigned int u = v.u;
    return (unsigned short)((u + 0x7FFFu + ((u >> 16) & 1u)) >> 16);
}
__device__ __forceinline__ float bf2f(unsigned short s) {
    union { unsigned int u; float f; } v; v.u = ((unsigned int)s) << 16;
    return v.f;
}

// ---------------------------------------------------------------------------
// Pass 1: repack x (fp32 [b][c][34][34]) -> x2 (bf16 [h][w][b][c]).
// ---------------------------------------------------------------------------
__global__ __launch_bounds__(256) void repack_x(const float* __restrict__ x,
                                                unsigned short* __restrict__ x2) {
    const int ph = blockIdx.x;           // (b/2)*34 + h
    const int b0 = (ph / H_) * 2;
    const int h  = ph % H_;
    __shared__ unsigned short tile[2][C_][H_ + 2];
    const int t = threadIdx.x;
    for (int e = t; e < 2 * C_ * H_; e += 256) {
        const int bb = e / (C_ * H_);
        const int rem = e % (C_ * H_);
        const int c = rem / H_, w = rem % H_;
        tile[bb][c][w] = f2bf(x[(((size_t)(b0 + bb) * C_ + c) * H_ + h) * H_ + w]);
    }
    __syncthreads();
    for (int e = t; e < H_ * 64; e += 256) {
        const int w = e >> 6;
        const int idx = e & 63;            // bb*32 + c
        x2[((size_t)(h * H_ + w)) * BC + b0 * C_ + idx] = tile[idx >> 5][idx & 31][w];
    }
}

// ---------------------------------------------------------------------------
// Main (fused): block = (i, j-quarter of 4, o-quarter of 16).
// Weight slice per p = contiguous 144 B (4 j x 9 k) -> aligned dwordx4 staging.
// LDS Wl is XOR-swizzled: element (d=jj*9+k, pl=o_l*32+c) lives at
//   d*512 + ((pl>>3) ^ ((d>>2)&7))*8 + (pl&7)
// -> staging writes ~conflict-free (8 distinct banks per same-pl lane group),
//    frag reads stay 16-B aligned dense ds_read_b128 rows.
// K-loop: per kh, the 6 distinct (w) x2 row-fragments are loaded ONCE into
// registers (12 independent 1 KB wave-loads) and reused across (kw,jj).
// Output: ws bf16 [pos][o][b] (bias deferred to transpose_out).
// ---------------------------------------------------------------------------
__global__ __launch_bounds__(256, 4) void lc_fused(const unsigned short* __restrict__ x2,
                                                   const float* __restrict__ weight,
                                                   unsigned short* __restrict__ ws) {
    __shared__ __align__(16) unsigned short Wl[36 * 512];  // 36,864 B

    const int bid = blockIdx.x;
    const int jq = bid & 7;            // j-quarter -> XCD id (round-robin bid%8)
    const int i  = (bid >> 3) & 31;
    const int oq = bid >> 8;           // o-quarter (16 o's)
    const int j0 = jq * 4;
    const int o0 = oq * 16;
    const int posbase = i * 32 + j0;   // multiple of 4 -> weight runs 16-B aligned
    const int t = threadIdx.x;

    // ---- stage weights: 512 p x 36 floats (contiguous per p), dwordx4 ----
    const float* wbase = weight + ((size_t)(o0 * C_) * NPOS + posbase) * K9;
#pragma unroll
    for (int r = 0; r < 18; ++r) {
        const int idx = r * 256 + t;          // 0..4607
        const int pl = idx / 9;               // p_local 0..511
        const int d4 = idx % 9;               // dwordx4 index 0..8
        const f4a v = *(const f4a*)(wbase + (size_t)pl * (NPOS * K9) + d4 * 4);
        const int sw = ((pl >> 3) ^ (d4 & 7)) * 8 + (pl & 7);  // swizzled column
#pragma unroll
        for (int u = 0; u < 4; ++u)
            Wl[(d4 * 4 + u) * 512 + sw] = f2bf(v[u]);
    }
    __syncthreads();

    const int wv = t >> 6;      // wave -> b-band [wv*32, wv*32+32)
    const int l  = t & 63;
    const int lm = l & 15;      // o_local (B n-index) / A m-index
    const int q  = l >> 4;

    v4f acc[4][2];              // [jj][mt]
#pragma unroll
    for (int a = 0; a < 4; ++a)
#pragma unroll
        for (int m = 0; m < 2; ++m) acc[a][m] = (v4f){0.f, 0.f, 0.f, 0.f};

#pragma unroll
    for (int kh = 0; kh < 3; ++kh) {
        // load the 6 distinct x2 row-fragments for this kh once
        v8bf ax[6][2];
        const int rowbase = (i + kh) * H_ + j0;
#pragma unroll
        for (int w6 = 0; w6 < 6; ++w6) {
            const unsigned short* xrow = x2 + (size_t)(rowbase + w6) * BC;
            ax[w6][0] = *(const v8bf*)(xrow + (wv * 32 + lm) * C_ + q * 8);
            ax[w6][1] = *(const v8bf*)(xrow + (wv * 32 + 16 + lm) * C_ + q * 8);
        }
#pragma unroll
        for (int kw = 0; kw < 3; ++kw) {
            const int tap = kh * 3 + kw;
#pragma unroll
            for (int jj = 0; jj < 4; ++jj) {
                const int jk = jj * K9 + tap;
                const int g  = ((lm * 4 + q) ^ ((jk >> 2) & 7)) * 8;
                const v8bf bfr = *(const v8bf*)&Wl[jk * 512 + g];
                acc[jj][0] = __builtin_amdgcn_mfma_f32_16x16x32_bf16(
                    ax[kw + jj][0], bfr, acc[jj][0], 0, 0, 0);
                acc[jj][1] = __builtin_amdgcn_mfma_f32_16x16x32_bf16(
                    ax[kw + jj][1], bfr, acc[jj][1], 0, 0, 0);
            }
        }
    }

    // ---- epilogue: D col(lane&15)=o_local, row(q*4+r)=b_local ----
#pragma unroll
    for (int jj = 0; jj < 4; ++jj) {
        const int pos = posbase + jj;
        unsigned short* wp = ws + (size_t)pos * BO + (o0 + lm) * B_;
#pragma unroll
        for (int mt = 0; mt < 2; ++mt) {
            const int b = wv * 32 + mt * 16 + q * 4;
            ushort4 pk;
            pk.x = f2bf(acc[jj][mt][0]);
            pk.y = f2bf(acc[jj][mt][1]);
            pk.z = f2bf(acc[jj][mt][2]);
            pk.w = f2bf(acc[jj][mt][3]);
            *(ushort4*)(wp + b) = pk;
        }
    }
}

// ---------------------------------------------------------------------------
// Fallback (no workspace): per-pos kernel gathering straight from fp32.
// ---------------------------------------------------------------------------
__global__ __launch_bounds__(256) void lc_fallback(const float* __restrict__ x,
                                                   const float* __restrict__ weight,
                                                   const float* __restrict__ bias,
                                                   float* __restrict__ out) {
    const int pos = blockIdx.x;
    const int i = pos >> 5, j = pos & 31;
    const int t  = threadIdx.x;
    const int wv = t >> 6;
    const int l  = t & 63;
    const int lm = l & 15;
    const int q  = l >> 4;

    float bv[4];
#pragma unroll
    for (int nt = 0; nt < 4; ++nt)
        bv[nt] = bias[(size_t)(nt * 16 + lm) * NPOS + pos];

    v4f acc[2][4];
#pragma unroll
    for (int a = 0; a < 2; ++a)
#pragma unroll
        for (int n = 0; n < 4; ++n) acc[a][n] = (v4f){0.f, 0.f, 0.f, 0.f};

    for (int k = 0; k < K9; ++k) {
        const int kh = k / 3, kw = k % 3;
        v8bf af[2], bfr[4];
#pragma unroll
        for (int mt = 0; mt < 2; ++mt) {
            const int b = wv * 32 + mt * 16 + lm;
            union { v8bf v; unsigned short s[8]; } u;
#pragma unroll
            for (int cc = 0; cc < 8; ++cc)
                u.s[cc] = f2bf(x[(((size_t)b * C_ + q * 8 + cc) * H_ + (i + kh)) * H_ + (j + kw)]);
            af[mt] = u.v;
        }
#pragma unroll
        for (int nt = 0; nt < 4; ++nt) {
            union { v8bf v; unsigned short s[8]; } u;
#pragma unroll
            for (int cc = 0; cc < 8; ++cc) {
                const int p = (nt * 16 + lm) * C_ + q * 8 + cc;
                u.s[cc] = f2bf(weight[((size_t)p * NPOS + pos) * K9 + k]);
            }
            bfr[nt] = u.v;
        }
#pragma unroll
        for (int mt = 0; mt < 2; ++mt)
#pragma unroll
            for (int nt = 0; nt < 4; ++nt)
                acc[mt][nt] = __builtin_amdgcn_mfma_f32_16x16x32_bf16(
                    af[mt], bfr[nt], acc[mt][nt], 0, 0, 0);
    }
#pragma unroll
    for (int mt = 0; mt < 2; ++mt)
#pragma unroll
        for (int nt = 0; nt < 4; ++nt) {
            const int o = nt * 16 + lm;
#pragma unroll
            for (int r = 0; r < 4; ++r) {
                const int b = wv * 32 + mt * 16 + q * 4 + r;
                out[(size_t)(b * O_ + o) * NPOS + pos] = acc[mt][nt][r] + bv[nt];
            }
        }
}

// ---------------------------------------------------------------------------
// Pass 3: ws bf16 [pos][o][b] -> out fp32 [b][o][pos], + bias[o][pos].
// Block = (o, b-tile of 64, pos-tile of 64); 64x64 tile via LDS (+1 pad).
// ---------------------------------------------------------------------------
__global__ __launch_bounds__(256) void transpose_out(const unsigned short* __restrict__ ws,
                                                     const float* __restrict__ bias,
                                                     float* __restrict__ out) {
    __shared__ float tile[64][65];
    const int tb = blockIdx.x;             // 0..2047
    const int o  = tb >> 5;                // 64
    const int bt = (tb >> 4) & 1;          // 2 b-tiles
    const int pt = tb & 15;                // 16 pos-tiles
    const int b0 = bt * 64;
    const int p0 = pt * 64;
    const int tx = threadIdx.x & 63;
    const int ty = threadIdx.x >> 6;
#pragma unroll
    for (int r = 0; r < 16; ++r) {
        const int pr = r * 4 + ty;
        tile[pr][tx] = bf2f(ws[(size_t)(p0 + pr) * BO + o * B_ + b0 + tx]);
    }
    const float bvt = bias[(size_t)o * NPOS + p0 + tx];   // lane's pos is fixed below
    __syncthreads();
#pragma unroll
    for (int r = 0; r < 16; ++r) {
        const int br = r * 4 + ty;
        out[((size_t)(b0 + br) * O_ + o) * NPOS + p0 + tx] = tile[tx][br] + bvt;
    }
}

// ---------------------------------------------------------------------------
extern "C" void kernel_launch(void* const* d_in, const int* in_sizes, int n_in,
                              void* d_out, int out_size, void* d_ws, size_t ws_size,
                              hipStream_t stream) {
    const float* x      = (const float*)d_in[0];
    const float* weight = (const float*)d_in[1];
    const float* bias   = (const float*)d_in[2];
    float* out          = (float*)d_out;

    const size_t WSB = (size_t)NPOS * BO * sizeof(unsigned short);        // 16,777,216
    const size_t X2B = (size_t)H_ * H_ * BC * sizeof(unsigned short);     //  9,469,952

    if (ws_size >= WSB + X2B) {
        unsigned short* wsout = (unsigned short*)d_ws;
        unsigned short* x2 = (unsigned short*)((char*)d_ws + WSB);
        repack_x<<<(B_ / 2) * H_, 256, 0, stream>>>(x, x2);
        lc_fused<<<1024, 256, 0, stream>>>(x2, weight, wsout);
        transpose_out<<<2048, 256, 0, stream>>>(wsout, bias, out);
    } else {
        lc_fallback<<<NPOS, 256, 0, stream>>>(x, weight, bias, out);
    }
}